// Round 5
// baseline (682.612 us; speedup 1.0000x reference)
//
#include <hip/hip_runtime.h>
#include <math.h>

#define Nn 50000
#define Ee 600000
#define Bg 128      // batches (graphs)
#define Hd 128      // hidden dim
#define Kt 30       // sortpool K
#define CO 32       // conv out channels
#define KW 5        // conv kernel
#define LOUT 26     // K - KW + 1
#define CAP 2048    // per-batch node cap for topk LDS (max real count ~460)
#define SCB 196     // ceil(50000/256) scan blocks
#define CVO 8       // conv o's per block (grid y = CO/CVO = 4)

typedef float v4f __attribute__((ext_vector_type(4)));

// ---------------- init ----------------
__global__ void init_kernel(int* __restrict__ deg_i, int* __restrict__ cnt,
                            int* __restrict__ bstart) {
    int i = blockIdx.x * 256 + threadIdx.x;
    if (i < Nn) { deg_i[i] = 1; cnt[i] = 0; }   // deg starts at 1 (self loop)
    if (i <= Bg) bstart[i] = Nn;                // sentinel
}

// ---------------- degree histogram + batch starts (boundary detect) ----------
__global__ void count_kernel(const int* __restrict__ ei, const int* __restrict__ batch,
                             int* __restrict__ deg_i, int* __restrict__ bstart) {
    int i = blockIdx.x * 256 + threadIdx.x;
    if (i < Ee) atomicAdd(&deg_i[ei[Ee + i]], 1);       // col = edge_index[1]
    if (i < Nn) {
        int b = batch[i];
        if (i == 0) {
            bstart[b] = 0;
        } else {
            int bp = batch[i - 1];
            if (bp != b) bstart[b] = i;
        }
    }
}

// ---------------- scan phase A: block sums of (deg-1), dinv ----------------
__global__ __launch_bounds__(256) void scanA_kernel(const int* __restrict__ deg_i,
                            float* __restrict__ dinv, int* __restrict__ bsum) {
    __shared__ int s[256];
    int tid = threadIdx.x;
    int i = blockIdx.x * 256 + tid;
    int v = 0;
    if (i < Nn) {
        int d = deg_i[i];
        dinv[i] = 1.0f / sqrtf((float)d);
        v = d - 1;
    }
    s[tid] = v;
    __syncthreads();
    for (int off = 128; off > 0; off >>= 1) {
        if (tid < off) s[tid] += s[tid + off];
        __syncthreads();
    }
    if (tid == 0) bsum[blockIdx.x] = s[0];
}

// ---------------- scan phase B: scan block sums; fix empty batches ----------
__global__ __launch_bounds__(256) void scanB_kernel(const int* __restrict__ bsum,
                            int* __restrict__ boff, int* __restrict__ bstart) {
    __shared__ int s[256];
    int tid = threadIdx.x;
    int v = (tid < SCB) ? bsum[tid] : 0;
    s[tid] = v;
    __syncthreads();
    for (int off = 1; off < 256; off <<= 1) {
        int t = (tid >= off) ? s[tid - off] : 0;
        __syncthreads();
        s[tid] += t;
        __syncthreads();
    }
    if (tid < SCB) boff[tid] = s[tid] - v;   // exclusive
    if (tid == 0) {   // empty batches inherit next start (batch array sorted)
        for (int b = Bg - 1; b >= 0; --b)
            if (bstart[b] == Nn) bstart[b] = bstart[b + 1];
    }
}

// ---------------- scan phase C: row_ptr = offset + local inclusive scan -----
__global__ __launch_bounds__(256) void scanC_kernel(const int* __restrict__ deg_i,
                            const int* __restrict__ boff, int* __restrict__ row_ptr) {
    __shared__ int s[256];
    int tid = threadIdx.x;
    int i = blockIdx.x * 256 + tid;
    int v = (i < Nn) ? deg_i[i] - 1 : 0;
    s[tid] = v;
    __syncthreads();
    for (int off = 1; off < 256; off <<= 1) {
        int t = (tid >= off) ? s[tid - off] : 0;
        __syncthreads();
        s[tid] += t;
        __syncthreads();
    }
    if (i < Nn) row_ptr[i + 1] = s[tid] + boff[blockIdx.x];
    if (i == 0) row_ptr[0] = 0;
}

// ---------------- CSR fill (edges grouped by destination col) ----------------
__global__ void fill_kernel(const int* __restrict__ ei, const int* __restrict__ row_ptr,
                            int* __restrict__ cnt, int* __restrict__ csr_src) {
    int e = blockIdx.x * 256 + threadIdx.x;
    if (e >= Ee) return;
    int c = ei[Ee + e];
    int r = ei[e];
    int p = row_ptr[c] + atomicAdd(&cnt[c], 1);
    csr_src[p] = r;
}

// ---------------- matmul: hw[i] = dinv[i] * (Hin[i] @ W) ----------------
#define MMR 64
__global__ __launch_bounds__(256) void mm_kernel(const float* __restrict__ Hin,
                            const float* __restrict__ W, const float* __restrict__ dinv,
                            float* __restrict__ hw) {
    __shared__ float hl[MMR * Hd];
    int row0 = blockIdx.x * MMR;
    int tid = threadIdx.x;
    for (int i = tid; i < MMR * Hd / 4; i += 256) {
        int r = i >> 5;
        int gr = row0 + r;
        float4 v = make_float4(0.f, 0.f, 0.f, 0.f);
        if (gr < Nn) v = ((const float4*)(Hin + (size_t)gr * Hd))[i & 31];
        ((float4*)hl)[i] = v;
    }
    __syncthreads();
    int cg = tid & 31;
    int rg = tid >> 5;
    float acc[8][4];
#pragma unroll
    for (int i = 0; i < 8; ++i)
#pragma unroll
        for (int j = 0; j < 4; ++j) acc[i][j] = 0.f;

    const float* hb = hl + rg * 8 * Hd;
#pragma unroll 4
    for (int k = 0; k < Hd; ++k) {
        float4 w = *(const float4*)(W + k * Hd + cg * 4);
#pragma unroll
        for (int i = 0; i < 8; ++i) {
            float hv = hb[i * Hd + k];
            acc[i][0] = fmaf(hv, w.x, acc[i][0]);
            acc[i][1] = fmaf(hv, w.y, acc[i][1]);
            acc[i][2] = fmaf(hv, w.z, acc[i][2]);
            acc[i][3] = fmaf(hv, w.w, acc[i][3]);
        }
    }
#pragma unroll
    for (int i = 0; i < 8; ++i) {
        int r = row0 + rg * 8 + i;
        if (r < Nn) {
            float s = dinv[r];
            float4 o = make_float4(acc[i][0] * s, acc[i][1] * s, acc[i][2] * s, acc[i][3] * s);
            *(float4*)(hw + (size_t)r * Hd + cg * 4) = o;
        }
    }
}

// ---------------- aggregation, feature-chunked for L2 residency ----------------
// h[i][chunk] = relu(dinv[i]*(hw[i][chunk] + sum_src hw[src][chunk]) + b[chunk])
// grid (782, 8): chunk = blockIdx.y -> 16 floats, working set 3.2 MB < 4 MB XCD L2.
// wave = 16 node-groups x 4 lanes (float4 each). csr loads + hout stores are
// nontemporal so the streams don't evict the chunk from L2.
__global__ __launch_bounds__(256) void agg_kernel(const float* __restrict__ hw,
                            const int* __restrict__ row_ptr, const int* __restrict__ csr_src,
                            const float* __restrict__ dinv, const float* __restrict__ bias,
                            float* __restrict__ hout) {
    int chunk = blockIdx.y;
    int wave = threadIdx.x >> 6;
    int lane = threadIdx.x & 63;
    int g = lane >> 2;          // node group 0..15
    int l4 = lane & 3;          // float4 within chunk
    int node = (blockIdx.x * 4 + wave) * 16 + g;
    if (node >= Nn) return;
    int fo = chunk * 4 + l4;    // float4 index within the 32-float4 row
    const v4f* hw4 = (const v4f*)hw;
    size_t rowbase = (size_t)node * 32;
    v4f a0 = hw4[rowbase + fo];   // self-loop term (hw pre-scaled by dinv[src])
    v4f a1 = 0.f, a2 = 0.f, a3 = 0.f;
    int e0 = row_ptr[node], e1 = row_ptr[node + 1];
    int e = e0;
    for (; e + 3 < e1; e += 4) {
        int s0 = __builtin_nontemporal_load(csr_src + e);
        int s1 = __builtin_nontemporal_load(csr_src + e + 1);
        int s2 = __builtin_nontemporal_load(csr_src + e + 2);
        int s3 = __builtin_nontemporal_load(csr_src + e + 3);
        a0 += hw4[(size_t)s0 * 32 + fo];
        a1 += hw4[(size_t)s1 * 32 + fo];
        a2 += hw4[(size_t)s2 * 32 + fo];
        a3 += hw4[(size_t)s3 * 32 + fo];
    }
    for (; e < e1; ++e) {
        int s0 = __builtin_nontemporal_load(csr_src + e);
        a0 += hw4[(size_t)s0 * 32 + fo];
    }
    v4f acc = (a0 + a1) + (a2 + a3);
    float d = dinv[node];
    v4f bv = ((const v4f*)bias)[fo];
    v4f o;
    o.x = fmaxf(fmaf(d, acc.x, bv.x), 0.f);
    o.y = fmaxf(fmaf(d, acc.y, bv.y), 0.f);
    o.z = fmaxf(fmaf(d, acc.z, bv.z), 0.f);
    o.w = fmaxf(fmaf(d, acc.w, bv.w), 0.f);
    __builtin_nontemporal_store(o, (v4f*)hout + rowbase + fo);
}

// ---------------- top-K per batch + gather pooled tile to xcg ----------------
__global__ __launch_bounds__(256) void topk_kernel(const float* __restrict__ h,
                            const int* __restrict__ bstart, float* __restrict__ xcg) {
    __shared__ float vals[CAP];
    __shared__ float rv[4];
    __shared__ int ri[4];
    __shared__ int selS[Kt];
    int b = blockIdx.x, tid = threadIdx.x;
    int s0 = bstart[b], s1 = bstart[b + 1];
    int n = s1 - s0;
    int nc = n < CAP ? n : CAP;
    for (int j = tid; j < nc; j += 256)
        vals[j] = h[(size_t)(s0 + j) * Hd + (Hd - 1)];
    __syncthreads();
    for (int k = 0; k < Kt; ++k) {
        float bv = -1.f;
        int bi = 0x7fffffff;
        for (int j = tid; j < nc; j += 256) {
            float v = vals[j];
            if (v > bv || (v == bv && j < bi)) { bv = v; bi = j; }
        }
        for (int off = 32; off > 0; off >>= 1) {
            float ov = __shfl_down(bv, off);
            int oi = __shfl_down(bi, off);
            if (ov > bv || (ov == bv && oi < bi)) { bv = ov; bi = oi; }
        }
        int wid = tid >> 6;
        if ((tid & 63) == 0) { rv[wid] = bv; ri[wid] = bi; }
        __syncthreads();
        if (tid == 0) {
            float fv = rv[0]; int fi = ri[0];
            for (int w = 1; w < 4; ++w) {
                if (rv[w] > fv || (rv[w] == fv && ri[w] < fi)) { fv = rv[w]; fi = ri[w]; }
            }
            if (k < n) {
                selS[k] = s0 + fi;
                vals[fi] = -1.f;   // relu output >= 0, so -1 can never win again
            } else {
                selS[k] = -1;
            }
        }
        __syncthreads();
    }
    // gather pooled tile: xcg[b][t][c]
    for (int i = tid; i < Kt * Hd; i += 256) {
        int t = i >> 7, c = i & 127;
        int s = selS[t];
        xcg[((size_t)b * Kt + t) * Hd + c] = (s >= 0) ? h[(size_t)s * Hd + c] : 0.f;
    }
}

// ---------------- conv_w transpose: wT2[o][k][ci] = conv_w[o][ci][k] ---------
__global__ void wtr_kernel(const float* __restrict__ conv_w, float* __restrict__ wT2) {
    int i = blockIdx.x * 256 + threadIdx.x;
    if (i >= CO * KW * Hd) return;
    int ci = i & 127;
    int r = i >> 7;          // o*KW + k
    int o = r / KW, k = r - o * KW;
    wT2[i] = conv_w[((size_t)o * Hd + ci) * KW + k];
}

// ---------------- conv: flatg[b][o][t] = relu(conv_b[o] + xc . w) -----------
__global__ __launch_bounds__(256) void conv_kernel(const float* __restrict__ xcg,
                            const float* __restrict__ wT2, const float* __restrict__ conv_b,
                            float* __restrict__ flatg) {
    __shared__ float xcl[Kt][130];
    int b = blockIdx.x, q = blockIdx.y;
    int o0 = q * CVO;
    int tid = threadIdx.x;
    for (int i = tid; i < Kt * 32; i += 256) {   // 960 float4
        int t = i >> 5, c4 = i & 31;
        float4 v = ((const float4*)(xcg + ((size_t)b * Kt + t) * Hd))[c4];
        float2* dst = (float2*)&xcl[t][c4 * 4];
        dst[0] = make_float2(v.x, v.y);
        dst[1] = make_float2(v.z, v.w);
    }
    __syncthreads();
    int idx = tid;
    if (idx < CVO * LOUT) {
        int op = idx / LOUT, t = idx - op * LOUT;
        int o = o0 + op;
        float acc = conv_b[o];
#pragma unroll
        for (int k = 0; k < KW; ++k) {
            const float* xr = &xcl[t + k][0];
            const float* wr = wT2 + ((size_t)o * KW + k) * Hd;
#pragma unroll 8
            for (int c4 = 0; c4 < 32; ++c4) {
                float2 xa = *(const float2*)(xr + c4 * 4);
                float2 xb = *(const float2*)(xr + c4 * 4 + 2);
                float4 wv = *(const float4*)(wr + c4 * 4);
                acc = fmaf(xa.x, wv.x, acc);
                acc = fmaf(xa.y, wv.y, acc);
                acc = fmaf(xb.x, wv.z, acc);
                acc = fmaf(xb.y, wv.w, acc);
            }
        }
        flatg[((size_t)b * CO + o) * LOUT + t] = fmaxf(acc, 0.f);
    }
}

// ---------------- lin1 partials: pz[b][q8][h] over m-chunks of 104 ----------
__global__ __launch_bounds__(256) void lin1_kernel(const float* __restrict__ flatg,
                            const float* __restrict__ l1w, float* __restrict__ pz) {
    int b = blockIdx.x, mq = blockIdx.y;    // grid (Bg, 4)
    int tid = threadIdx.x;
    int hh = tid & 127, half = tid >> 7;
    int m0 = mq * 208 + half * 104;
    const float* fp = flatg + (size_t)b * (CO * LOUT) + m0;
    const float* wp = l1w + (size_t)m0 * Hd + hh;
    float acc = 0.f;
#pragma unroll 8
    for (int m = 0; m < 104; ++m)
        acc = fmaf(fp[m], wp[(size_t)m * Hd], acc);
    pz[((size_t)b * 8 + mq * 2 + half) * Hd + hh] = acc;
}

// ---------------- head finish: z = relu(sum pz + b1); out = z@l2w + b2 ------
__global__ __launch_bounds__(128) void headfin_kernel(const float* __restrict__ pz,
                            const float* __restrict__ l1b, const float* __restrict__ l2w,
                            const float* __restrict__ l2b, float* __restrict__ out) {
    __shared__ float z[Hd];
    int b = blockIdx.x, tid = threadIdx.x;
    float acc = l1b[tid];
#pragma unroll
    for (int q = 0; q < 8; ++q)
        acc += pz[((size_t)b * 8 + q) * Hd + tid];
    z[tid] = fmaxf(acc, 0.f);
    __syncthreads();
    if (tid < 10) {
        float a2 = l2b[tid];
        for (int j = 0; j < Hd; ++j)
            a2 = fmaf(z[j], l2w[j * 10 + tid], a2);
        out[b * 10 + tid] = a2;
    }
}

extern "C" void kernel_launch(void* const* d_in, const int* in_sizes, int n_in,
                              void* d_out, int out_size, void* d_ws, size_t ws_size,
                              hipStream_t stream) {
    const float* x      = (const float*)d_in[0];
    const int*   ei     = (const int*)d_in[1];
    const int*   batch  = (const int*)d_in[2];
    const float* W0     = (const float*)d_in[3];
    const float* b0     = (const float*)d_in[4];
    const float* W1     = (const float*)d_in[5];
    const float* b1     = (const float*)d_in[6];
    const float* W2     = (const float*)d_in[7];
    const float* b2     = (const float*)d_in[8];
    const float* conv_w = (const float*)d_in[9];
    const float* conv_b = (const float*)d_in[10];
    const float* l1w    = (const float*)d_in[11];
    const float* l1b    = (const float*)d_in[12];
    const float* l2w    = (const float*)d_in[13];
    const float* l2b    = (const float*)d_in[14];
    float* out = (float*)d_out;

    // workspace layout
    int* wsI = (int*)d_ws;
    size_t off = 0;
    int*   deg_i   = wsI + off; off += Nn;
    int*   cnt     = wsI + off; off += Nn;
    int*   row_ptr = wsI + off; off += 50004;
    int*   bstart  = wsI + off; off += 132;
    float* dinv    = (float*)(wsI + off); off += Nn;
    int*   bsum    = wsI + off; off += 256;
    int*   boff    = wsI + off; off += 256;
    int*   csr_src = wsI + off; off += Ee;
    off = (off + 3) & ~(size_t)3;        // 16B align
    float* hw    = (float*)(wsI + off); off += (size_t)Nn * Hd;
    float* hbuf  = (float*)(wsI + off); off += (size_t)Nn * Hd;
    float* xcg   = (float*)(wsI + off); off += (size_t)Bg * Kt * Hd;
    float* wT2   = (float*)(wsI + off); off += CO * KW * Hd;
    float* flatg = (float*)(wsI + off); off += (size_t)Bg * CO * LOUT;
    float* pz    = (float*)(wsI + off); off += (size_t)Bg * 8 * Hd;

    // 1. init
    init_kernel<<<(Nn + 255) / 256, 256, 0, stream>>>(deg_i, cnt, bstart);
    // 2. degree histogram + batch starts
    count_kernel<<<(Ee + 255) / 256, 256, 0, stream>>>(ei, batch, deg_i, bstart);
    // conv_w transpose (independent; cheap)
    wtr_kernel<<<(CO * KW * Hd + 255) / 256, 256, 0, stream>>>(conv_w, wT2);
    // 3. multi-block exclusive scan -> row_ptr, dinv; fix bstart
    scanA_kernel<<<SCB, 256, 0, stream>>>(deg_i, dinv, bsum);
    scanB_kernel<<<1, 256, 0, stream>>>(bsum, boff, bstart);
    scanC_kernel<<<SCB, 256, 0, stream>>>(deg_i, boff, row_ptr);
    // 4. CSR fill
    fill_kernel<<<(Ee + 255) / 256, 256, 0, stream>>>(ei, row_ptr, cnt, csr_src);

    // 5. three GCN layers
    dim3 mmGrid((Nn + MMR - 1) / MMR);
    dim3 aggGrid((Nn + 63) / 64, 8);
    mm_kernel<<<mmGrid, 256, 0, stream>>>(x, W0, dinv, hw);
    agg_kernel<<<aggGrid, 256, 0, stream>>>(hw, row_ptr, csr_src, dinv, b0, hbuf);
    mm_kernel<<<mmGrid, 256, 0, stream>>>(hbuf, W1, dinv, hw);
    agg_kernel<<<aggGrid, 256, 0, stream>>>(hw, row_ptr, csr_src, dinv, b1, hbuf);
    mm_kernel<<<mmGrid, 256, 0, stream>>>(hbuf, W2, dinv, hw);
    agg_kernel<<<aggGrid, 256, 0, stream>>>(hw, row_ptr, csr_src, dinv, b2, hbuf);

    // 6. sort-pool top-K + gather
    topk_kernel<<<Bg, 256, 0, stream>>>(hbuf, bstart, xcg);
    // 7. head pipeline: conv -> lin1 partials -> finish
    conv_kernel<<<dim3(Bg, CO / CVO), 256, 0, stream>>>(xcg, wT2, conv_b, flatg);
    lin1_kernel<<<dim3(Bg, 4), 256, 0, stream>>>(flatg, l1w, pz);
    headfin_kernel<<<Bg, 128, 0, stream>>>(pz, l1b, l2w, l2b, out);
}

// Round 6
// 580.759 us; speedup vs baseline: 1.1754x; 1.1754x over previous
//
#include <hip/hip_runtime.h>
#include <math.h>

#define Nn 50000
#define Ee 600000
#define Bg 128      // batches (graphs)
#define Hd 128      // hidden dim
#define Kt 30       // sortpool K
#define CO 32       // conv out channels
#define KW 5        // conv kernel
#define LOUT 26     // K - KW + 1
#define CAP 2048    // per-batch node cap for topk LDS (max real count ~460)
#define SCB 196     // ceil(50000/256) scan blocks
#define CVO 8       // conv o's per block (grid y = CO/CVO = 4)
#define NPAD 50048  // node count padded for slab alignment
#define SLABF ((size_t)NPAD * 16)   // floats per chunk slab (16 floats = 64B per node)

typedef float v4f __attribute__((ext_vector_type(4)));

// ---------------- init ----------------
__global__ void init_kernel(int* __restrict__ deg_i, int* __restrict__ cnt,
                            int* __restrict__ bstart) {
    int i = blockIdx.x * 256 + threadIdx.x;
    if (i < Nn) { deg_i[i] = 1; cnt[i] = 0; }   // deg starts at 1 (self loop)
    if (i <= Bg) bstart[i] = Nn;                // sentinel
}

// ---------------- degree histogram + batch starts (boundary detect) ----------
__global__ void count_kernel(const int* __restrict__ ei, const int* __restrict__ batch,
                             int* __restrict__ deg_i, int* __restrict__ bstart) {
    int i = blockIdx.x * 256 + threadIdx.x;
    if (i < Ee) atomicAdd(&deg_i[ei[Ee + i]], 1);       // col = edge_index[1]
    if (i < Nn) {
        int b = batch[i];
        if (i == 0) {
            bstart[b] = 0;
        } else {
            int bp = batch[i - 1];
            if (bp != b) bstart[b] = i;
        }
    }
}

// ---------------- scan phase A: block sums of (deg-1), dinv ----------------
__global__ __launch_bounds__(256) void scanA_kernel(const int* __restrict__ deg_i,
                            float* __restrict__ dinv, int* __restrict__ bsum) {
    __shared__ int s[256];
    int tid = threadIdx.x;
    int i = blockIdx.x * 256 + tid;
    int v = 0;
    if (i < Nn) {
        int d = deg_i[i];
        dinv[i] = 1.0f / sqrtf((float)d);
        v = d - 1;
    }
    s[tid] = v;
    __syncthreads();
    for (int off = 128; off > 0; off >>= 1) {
        if (tid < off) s[tid] += s[tid + off];
        __syncthreads();
    }
    if (tid == 0) bsum[blockIdx.x] = s[0];
}

// ---------------- scan phase B: scan block sums; fix empty batches ----------
__global__ __launch_bounds__(256) void scanB_kernel(const int* __restrict__ bsum,
                            int* __restrict__ boff, int* __restrict__ bstart) {
    __shared__ int s[256];
    int tid = threadIdx.x;
    int v = (tid < SCB) ? bsum[tid] : 0;
    s[tid] = v;
    __syncthreads();
    for (int off = 1; off < 256; off <<= 1) {
        int t = (tid >= off) ? s[tid - off] : 0;
        __syncthreads();
        s[tid] += t;
        __syncthreads();
    }
    if (tid < SCB) boff[tid] = s[tid] - v;   // exclusive
    if (tid == 0) {   // empty batches inherit next start (batch array sorted)
        for (int b = Bg - 1; b >= 0; --b)
            if (bstart[b] == Nn) bstart[b] = bstart[b + 1];
    }
}

// ---------------- scan phase C: row_ptr = offset + local inclusive scan -----
__global__ __launch_bounds__(256) void scanC_kernel(const int* __restrict__ deg_i,
                            const int* __restrict__ boff, int* __restrict__ row_ptr) {
    __shared__ int s[256];
    int tid = threadIdx.x;
    int i = blockIdx.x * 256 + tid;
    int v = (i < Nn) ? deg_i[i] - 1 : 0;
    s[tid] = v;
    __syncthreads();
    for (int off = 1; off < 256; off <<= 1) {
        int t = (tid >= off) ? s[tid - off] : 0;
        __syncthreads();
        s[tid] += t;
        __syncthreads();
    }
    if (i < Nn) row_ptr[i + 1] = s[tid] + boff[blockIdx.x];
    if (i == 0) row_ptr[0] = 0;
}

// ---------------- CSR fill (edges grouped by destination col) ----------------
__global__ void fill_kernel(const int* __restrict__ ei, const int* __restrict__ row_ptr,
                            int* __restrict__ cnt, int* __restrict__ csr_src) {
    int e = blockIdx.x * 256 + threadIdx.x;
    if (e >= Ee) return;
    int c = ei[Ee + e];
    int r = ei[e];
    int p = row_ptr[c] + atomicAdd(&cnt[c], 1);
    csr_src[p] = r;
}

// ---------------- matmul: hw_c[chunk][i][16f] = dinv[i] * (Hin[i] @ W) --------
// reads row-major Hin; writes CHUNK-MAJOR product (8 slabs of NPAD x 16 floats)
#define MMR 64
__global__ __launch_bounds__(256) void mm_kernel(const float* __restrict__ Hin,
                            const float* __restrict__ W, const float* __restrict__ dinv,
                            float* __restrict__ hw) {
    __shared__ float hl[MMR * Hd];
    int row0 = blockIdx.x * MMR;
    int tid = threadIdx.x;
    for (int i = tid; i < MMR * Hd / 4; i += 256) {
        int r = i >> 5;
        int gr = row0 + r;
        float4 v = make_float4(0.f, 0.f, 0.f, 0.f);
        if (gr < Nn) v = ((const float4*)(Hin + (size_t)gr * Hd))[i & 31];
        ((float4*)hl)[i] = v;
    }
    __syncthreads();
    int cg = tid & 31;
    int rg = tid >> 5;
    float acc[8][4];
#pragma unroll
    for (int i = 0; i < 8; ++i)
#pragma unroll
        for (int j = 0; j < 4; ++j) acc[i][j] = 0.f;

    const float* hb = hl + rg * 8 * Hd;
#pragma unroll 4
    for (int k = 0; k < Hd; ++k) {
        float4 w = *(const float4*)(W + k * Hd + cg * 4);
#pragma unroll
        for (int i = 0; i < 8; ++i) {
            float hv = hb[i * Hd + k];
            acc[i][0] = fmaf(hv, w.x, acc[i][0]);
            acc[i][1] = fmaf(hv, w.y, acc[i][1]);
            acc[i][2] = fmaf(hv, w.z, acc[i][2]);
            acc[i][3] = fmaf(hv, w.w, acc[i][3]);
        }
    }
    int chunk = cg >> 2;      // 16-float chunk this thread's 4 cols fall in
    int q4 = cg & 3;          // float4 within chunk
    float* slab = hw + (size_t)chunk * SLABF + q4 * 4;
#pragma unroll
    for (int i = 0; i < 8; ++i) {
        int r = row0 + rg * 8 + i;
        if (r < Nn) {
            float s = dinv[r];
            float4 o = make_float4(acc[i][0] * s, acc[i][1] * s, acc[i][2] * s, acc[i][3] * s);
            *(float4*)(slab + (size_t)r * 16) = o;
        }
    }
}

// ---------------- aggregation, chunk-major + XCD-pinned chunks ----------------
// h[i][16f chunk] = relu(dinv[i]*(hw_c[chunk][i] + sum_src hw_c[chunk][src]) + b[chunk])
// chunk = blockIdx.x & 7: consecutive blocks dispatch round-robin over the 8 XCDs,
// so each XCD works one 3.2 MB slab -> resident in its 4 MB L2.
// wave = 16 node-groups x 4 lanes (float4 each). csr loads nontemporal.
__global__ __launch_bounds__(256) void agg_kernel(const float* __restrict__ hw,
                            const int* __restrict__ row_ptr, const int* __restrict__ csr_src,
                            const float* __restrict__ dinv, const float* __restrict__ bias,
                            float* __restrict__ hout) {
    int chunk = blockIdx.x & 7;
    int slice = blockIdx.x >> 3;
    int wave = threadIdx.x >> 6;
    int lane = threadIdx.x & 63;
    int g = lane >> 2;          // node group 0..15
    int l4 = lane & 3;          // float4 within chunk
    int node = (slice * 4 + wave) * 16 + g;
    if (node >= Nn) return;
    const v4f* slab = (const v4f*)(hw + (size_t)chunk * SLABF);   // [node][4 x v4f]
    v4f a0 = slab[(size_t)node * 4 + l4];   // self-loop (hw pre-scaled by dinv[src])
    v4f a1 = 0.f, a2 = 0.f, a3 = 0.f;
    int e0 = row_ptr[node], e1 = row_ptr[node + 1];
    int e = e0;
    for (; e + 3 < e1; e += 4) {
        int s0 = __builtin_nontemporal_load(csr_src + e);
        int s1 = __builtin_nontemporal_load(csr_src + e + 1);
        int s2 = __builtin_nontemporal_load(csr_src + e + 2);
        int s3 = __builtin_nontemporal_load(csr_src + e + 3);
        a0 += slab[(size_t)s0 * 4 + l4];
        a1 += slab[(size_t)s1 * 4 + l4];
        a2 += slab[(size_t)s2 * 4 + l4];
        a3 += slab[(size_t)s3 * 4 + l4];
    }
    for (; e < e1; ++e) {
        int s0 = __builtin_nontemporal_load(csr_src + e);
        a0 += slab[(size_t)s0 * 4 + l4];
    }
    v4f acc = (a0 + a1) + (a2 + a3);
    float d = dinv[node];
    v4f bv = ((const v4f*)bias)[chunk * 4 + l4];
    v4f o;
    o.x = fmaxf(fmaf(d, acc.x, bv.x), 0.f);
    o.y = fmaxf(fmaf(d, acc.y, bv.y), 0.f);
    o.z = fmaxf(fmaf(d, acc.z, bv.z), 0.f);
    o.w = fmaxf(fmaf(d, acc.w, bv.w), 0.f);
    ((v4f*)hout)[(size_t)node * 32 + chunk * 4 + l4] = o;   // row-major output
}

// ---------------- top-K per batch + gather pooled tile to xcg ----------------
__global__ __launch_bounds__(256) void topk_kernel(const float* __restrict__ h,
                            const int* __restrict__ bstart, float* __restrict__ xcg) {
    __shared__ float vals[CAP];
    __shared__ float rv[4];
    __shared__ int ri[4];
    __shared__ int selS[Kt];
    int b = blockIdx.x, tid = threadIdx.x;
    int s0 = bstart[b], s1 = bstart[b + 1];
    int n = s1 - s0;
    int nc = n < CAP ? n : CAP;
    for (int j = tid; j < nc; j += 256)
        vals[j] = h[(size_t)(s0 + j) * Hd + (Hd - 1)];
    __syncthreads();
    for (int k = 0; k < Kt; ++k) {
        float bv = -1.f;
        int bi = 0x7fffffff;
        for (int j = tid; j < nc; j += 256) {
            float v = vals[j];
            if (v > bv || (v == bv && j < bi)) { bv = v; bi = j; }
        }
        for (int off = 32; off > 0; off >>= 1) {
            float ov = __shfl_down(bv, off);
            int oi = __shfl_down(bi, off);
            if (ov > bv || (ov == bv && oi < bi)) { bv = ov; bi = oi; }
        }
        int wid = tid >> 6;
        if ((tid & 63) == 0) { rv[wid] = bv; ri[wid] = bi; }
        __syncthreads();
        if (tid == 0) {
            float fv = rv[0]; int fi = ri[0];
            for (int w = 1; w < 4; ++w) {
                if (rv[w] > fv || (rv[w] == fv && ri[w] < fi)) { fv = rv[w]; fi = ri[w]; }
            }
            if (k < n) {
                selS[k] = s0 + fi;
                vals[fi] = -1.f;   // relu output >= 0, so -1 can never win again
            } else {
                selS[k] = -1;
            }
        }
        __syncthreads();
    }
    // gather pooled tile: xcg[b][t][c]
    for (int i = tid; i < Kt * Hd; i += 256) {
        int t = i >> 7, c = i & 127;
        int s = selS[t];
        xcg[((size_t)b * Kt + t) * Hd + c] = (s >= 0) ? h[(size_t)s * Hd + c] : 0.f;
    }
}

// ---------------- conv_w transpose: wT2[o][k][ci] = conv_w[o][ci][k] ---------
__global__ void wtr_kernel(const float* __restrict__ conv_w, float* __restrict__ wT2) {
    int i = blockIdx.x * 256 + threadIdx.x;
    if (i >= CO * KW * Hd) return;
    int ci = i & 127;
    int r = i >> 7;          // o*KW + k
    int o = r / KW, k = r - o * KW;
    wT2[i] = conv_w[((size_t)o * Hd + ci) * KW + k];
}

// ---------------- conv: flatg[b][o][t] = relu(conv_b[o] + xc . w) -----------
__global__ __launch_bounds__(256) void conv_kernel(const float* __restrict__ xcg,
                            const float* __restrict__ wT2, const float* __restrict__ conv_b,
                            float* __restrict__ flatg) {
    __shared__ float xcl[Kt][130];
    int b = blockIdx.x, q = blockIdx.y;
    int o0 = q * CVO;
    int tid = threadIdx.x;
    for (int i = tid; i < Kt * 32; i += 256) {   // 960 float4
        int t = i >> 5, c4 = i & 31;
        float4 v = ((const float4*)(xcg + ((size_t)b * Kt + t) * Hd))[c4];
        float2* dst = (float2*)&xcl[t][c4 * 4];
        dst[0] = make_float2(v.x, v.y);
        dst[1] = make_float2(v.z, v.w);
    }
    __syncthreads();
    int idx = tid;
    if (idx < CVO * LOUT) {
        int op = idx / LOUT, t = idx - op * LOUT;
        int o = o0 + op;
        float acc = conv_b[o];
#pragma unroll
        for (int k = 0; k < KW; ++k) {
            const float* xr = &xcl[t + k][0];
            const float* wr = wT2 + ((size_t)o * KW + k) * Hd;
#pragma unroll 8
            for (int c4 = 0; c4 < 32; ++c4) {
                float2 xa = *(const float2*)(xr + c4 * 4);
                float2 xb = *(const float2*)(xr + c4 * 4 + 2);
                float4 wv = *(const float4*)(wr + c4 * 4);
                acc = fmaf(xa.x, wv.x, acc);
                acc = fmaf(xa.y, wv.y, acc);
                acc = fmaf(xb.x, wv.z, acc);
                acc = fmaf(xb.y, wv.w, acc);
            }
        }
        flatg[((size_t)b * CO + o) * LOUT + t] = fmaxf(acc, 0.f);
    }
}

// ---------------- lin1 partials: pz[b][q8][h] over m-chunks of 104 ----------
__global__ __launch_bounds__(256) void lin1_kernel(const float* __restrict__ flatg,
                            const float* __restrict__ l1w, float* __restrict__ pz) {
    int b = blockIdx.x, mq = blockIdx.y;    // grid (Bg, 4)
    int tid = threadIdx.x;
    int hh = tid & 127, half = tid >> 7;
    int m0 = mq * 208 + half * 104;
    const float* fp = flatg + (size_t)b * (CO * LOUT) + m0;
    const float* wp = l1w + (size_t)m0 * Hd + hh;
    float acc = 0.f;
#pragma unroll 8
    for (int m = 0; m < 104; ++m)
        acc = fmaf(fp[m], wp[(size_t)m * Hd], acc);
    pz[((size_t)b * 8 + mq * 2 + half) * Hd + hh] = acc;
}

// ---------------- head finish: z = relu(sum pz + b1); out = z@l2w + b2 ------
__global__ __launch_bounds__(128) void headfin_kernel(const float* __restrict__ pz,
                            const float* __restrict__ l1b, const float* __restrict__ l2w,
                            const float* __restrict__ l2b, float* __restrict__ out) {
    __shared__ float z[Hd];
    int b = blockIdx.x, tid = threadIdx.x;
    float acc = l1b[tid];
#pragma unroll
    for (int q = 0; q < 8; ++q)
        acc += pz[((size_t)b * 8 + q) * Hd + tid];
    z[tid] = fmaxf(acc, 0.f);
    __syncthreads();
    if (tid < 10) {
        float a2 = l2b[tid];
        for (int j = 0; j < Hd; ++j)
            a2 = fmaf(z[j], l2w[j * 10 + tid], a2);
        out[b * 10 + tid] = a2;
    }
}

extern "C" void kernel_launch(void* const* d_in, const int* in_sizes, int n_in,
                              void* d_out, int out_size, void* d_ws, size_t ws_size,
                              hipStream_t stream) {
    const float* x      = (const float*)d_in[0];
    const int*   ei     = (const int*)d_in[1];
    const int*   batch  = (const int*)d_in[2];
    const float* W0     = (const float*)d_in[3];
    const float* b0     = (const float*)d_in[4];
    const float* W1     = (const float*)d_in[5];
    const float* b1     = (const float*)d_in[6];
    const float* W2     = (const float*)d_in[7];
    const float* b2     = (const float*)d_in[8];
    const float* conv_w = (const float*)d_in[9];
    const float* conv_b = (const float*)d_in[10];
    const float* l1w    = (const float*)d_in[11];
    const float* l1b    = (const float*)d_in[12];
    const float* l2w    = (const float*)d_in[13];
    const float* l2b    = (const float*)d_in[14];
    float* out = (float*)d_out;

    // workspace layout
    int* wsI = (int*)d_ws;
    size_t off = 0;
    int*   deg_i   = wsI + off; off += Nn;
    int*   cnt     = wsI + off; off += Nn;
    int*   row_ptr = wsI + off; off += 50004;
    int*   bstart  = wsI + off; off += 132;
    float* dinv    = (float*)(wsI + off); off += Nn;
    int*   bsum    = wsI + off; off += 256;
    int*   boff    = wsI + off; off += 256;
    int*   csr_src = wsI + off; off += Ee;
    off = (off + 3) & ~(size_t)3;        // 16B align
    float* hw    = (float*)(wsI + off); off += 8 * SLABF;          // chunk-major product
    float* hbuf  = (float*)(wsI + off); off += (size_t)Nn * Hd;    // row-major activations
    float* xcg   = (float*)(wsI + off); off += (size_t)Bg * Kt * Hd;
    float* wT2   = (float*)(wsI + off); off += CO * KW * Hd;
    float* flatg = (float*)(wsI + off); off += (size_t)Bg * CO * LOUT;
    float* pz    = (float*)(wsI + off); off += (size_t)Bg * 8 * Hd;

    // 1. init
    init_kernel<<<(Nn + 255) / 256, 256, 0, stream>>>(deg_i, cnt, bstart);
    // 2. degree histogram + batch starts
    count_kernel<<<(Ee + 255) / 256, 256, 0, stream>>>(ei, batch, deg_i, bstart);
    // conv_w transpose (independent; cheap)
    wtr_kernel<<<(CO * KW * Hd + 255) / 256, 256, 0, stream>>>(conv_w, wT2);
    // 3. multi-block exclusive scan -> row_ptr, dinv; fix bstart
    scanA_kernel<<<SCB, 256, 0, stream>>>(deg_i, dinv, bsum);
    scanB_kernel<<<1, 256, 0, stream>>>(bsum, boff, bstart);
    scanC_kernel<<<SCB, 256, 0, stream>>>(deg_i, boff, row_ptr);
    // 4. CSR fill
    fill_kernel<<<(Ee + 255) / 256, 256, 0, stream>>>(ei, row_ptr, cnt, csr_src);

    // 5. three GCN layers
    dim3 mmGrid((Nn + MMR - 1) / MMR);
    dim3 aggGrid(782 * 8);   // 782 node-slices x 8 chunks (chunk = blockIdx.x & 7)
    mm_kernel<<<mmGrid, 256, 0, stream>>>(x, W0, dinv, hw);
    agg_kernel<<<aggGrid, 256, 0, stream>>>(hw, row_ptr, csr_src, dinv, b0, hbuf);
    mm_kernel<<<mmGrid, 256, 0, stream>>>(hbuf, W1, dinv, hw);
    agg_kernel<<<aggGrid, 256, 0, stream>>>(hw, row_ptr, csr_src, dinv, b1, hbuf);
    mm_kernel<<<mmGrid, 256, 0, stream>>>(hbuf, W2, dinv, hw);
    agg_kernel<<<aggGrid, 256, 0, stream>>>(hw, row_ptr, csr_src, dinv, b2, hbuf);

    // 6. sort-pool top-K + gather
    topk_kernel<<<Bg, 256, 0, stream>>>(hbuf, bstart, xcg);
    // 7. head pipeline: conv -> lin1 partials -> finish
    conv_kernel<<<dim3(Bg, CO / CVO), 256, 0, stream>>>(xcg, wT2, conv_b, flatg);
    lin1_kernel<<<dim3(Bg, 4), 256, 0, stream>>>(flatg, l1w, pz);
    headfin_kernel<<<Bg, 128, 0, stream>>>(pz, l1b, l2w, l2b, out);
}

// Round 7
// 501.827 us; speedup vs baseline: 1.3603x; 1.1573x over previous
//
#include <hip/hip_runtime.h>
#include <math.h>

#define Nn 50000
#define Ee 600000
#define Bg 128      // batches (graphs)
#define Hd 128      // hidden dim
#define Kt 30       // sortpool K
#define CO 32       // conv out channels
#define KW 5        // conv kernel
#define LOUT 26     // K - KW + 1
#define CAP 2048    // per-batch node cap for topk LDS (max real count ~460)
#define SCB 196     // ceil(50000/256) scan blocks
#define CVO 8       // conv o's per block (grid y = CO/CVO = 4)

typedef float v2f __attribute__((ext_vector_type(2)));

// ---------------- init (+ conv_w transpose folded in) ----------------
__global__ void init_kernel(int* __restrict__ deg_i, int* __restrict__ cnt,
                            int* __restrict__ bstart,
                            const float* __restrict__ conv_w, float* __restrict__ wT2) {
    int i = blockIdx.x * 256 + threadIdx.x;
    if (i < Nn) { deg_i[i] = 1; cnt[i] = 0; }   // deg starts at 1 (self loop)
    if (i <= Bg) bstart[i] = Nn;                // sentinel
    if (i < CO * KW * Hd) {                     // wT2[o][k][ci] = conv_w[o][ci][k]
        int ci = i & 127;
        int r = i >> 7;          // o*KW + k
        int o = r / KW, k = r - o * KW;
        wT2[i] = conv_w[((size_t)o * Hd + ci) * KW + k];
    }
}

// ---------------- degree histogram + batch starts (boundary detect) ----------
__global__ void count_kernel(const int* __restrict__ ei, const int* __restrict__ batch,
                             int* __restrict__ deg_i, int* __restrict__ bstart) {
    int i = blockIdx.x * 256 + threadIdx.x;
    if (i < Ee) atomicAdd(&deg_i[ei[Ee + i]], 1);       // col = edge_index[1]
    if (i < Nn) {
        int b = batch[i];
        if (i == 0) {
            bstart[b] = 0;
        } else {
            int bp = batch[i - 1];
            if (bp != b) bstart[b] = i;
        }
    }
}

// ---------------- scan phase A: block sums of (deg-1), dinv ----------------
__global__ __launch_bounds__(256) void scanA_kernel(const int* __restrict__ deg_i,
                            float* __restrict__ dinv, int* __restrict__ bsum) {
    __shared__ int s[256];
    int tid = threadIdx.x;
    int i = blockIdx.x * 256 + tid;
    int v = 0;
    if (i < Nn) {
        int d = deg_i[i];
        dinv[i] = 1.0f / sqrtf((float)d);
        v = d - 1;
    }
    s[tid] = v;
    __syncthreads();
    for (int off = 128; off > 0; off >>= 1) {
        if (tid < off) s[tid] += s[tid + off];
        __syncthreads();
    }
    if (tid == 0) bsum[blockIdx.x] = s[0];
}

// ---------------- scan phase B: scan block sums; fix empty batches ----------
__global__ __launch_bounds__(256) void scanB_kernel(const int* __restrict__ bsum,
                            int* __restrict__ boff, int* __restrict__ bstart) {
    __shared__ int s[256];
    int tid = threadIdx.x;
    int v = (tid < SCB) ? bsum[tid] : 0;
    s[tid] = v;
    __syncthreads();
    for (int off = 1; off < 256; off <<= 1) {
        int t = (tid >= off) ? s[tid - off] : 0;
        __syncthreads();
        s[tid] += t;
        __syncthreads();
    }
    if (tid < SCB) boff[tid] = s[tid] - v;   // exclusive
    if (tid == 0) {   // empty batches inherit next start (batch array sorted)
        for (int b = Bg - 1; b >= 0; --b)
            if (bstart[b] == Nn) bstart[b] = bstart[b + 1];
    }
}

// ---------------- scan phase C: row_ptr = offset + local inclusive scan -----
__global__ __launch_bounds__(256) void scanC_kernel(const int* __restrict__ deg_i,
                            const int* __restrict__ boff, int* __restrict__ row_ptr) {
    __shared__ int s[256];
    int tid = threadIdx.x;
    int i = blockIdx.x * 256 + tid;
    int v = (i < Nn) ? deg_i[i] - 1 : 0;
    s[tid] = v;
    __syncthreads();
    for (int off = 1; off < 256; off <<= 1) {
        int t = (tid >= off) ? s[tid - off] : 0;
        __syncthreads();
        s[tid] += t;
        __syncthreads();
    }
    if (i < Nn) row_ptr[i + 1] = s[tid] + boff[blockIdx.x];
    if (i == 0) row_ptr[0] = 0;
}

// ---------------- CSR fill (edges grouped by destination col) ----------------
__global__ void fill_kernel(const int* __restrict__ ei, const int* __restrict__ row_ptr,
                            int* __restrict__ cnt, int* __restrict__ csr_src) {
    int e = blockIdx.x * 256 + threadIdx.x;
    if (e >= Ee) return;
    int c = ei[Ee + e];
    int r = ei[e];
    int p = row_ptr[c] + atomicAdd(&cnt[c], 1);
    csr_src[p] = r;
}

// ---------------- matmul: hw[i] = dinv[i] * (Hin[i] @ W), row-major out ------
#define MMR 64
__global__ __launch_bounds__(256) void mm_kernel(const float* __restrict__ Hin,
                            const float* __restrict__ W, const float* __restrict__ dinv,
                            float* __restrict__ hw) {
    __shared__ float hl[MMR * Hd];
    int row0 = blockIdx.x * MMR;
    int tid = threadIdx.x;
    for (int i = tid; i < MMR * Hd / 4; i += 256) {
        int r = i >> 5;
        int gr = row0 + r;
        float4 v = make_float4(0.f, 0.f, 0.f, 0.f);
        if (gr < Nn) v = ((const float4*)(Hin + (size_t)gr * Hd))[i & 31];
        ((float4*)hl)[i] = v;
    }
    __syncthreads();
    int cg = tid & 31;
    int rg = tid >> 5;
    float acc[8][4];
#pragma unroll
    for (int i = 0; i < 8; ++i)
#pragma unroll
        for (int j = 0; j < 4; ++j) acc[i][j] = 0.f;

    const float* hb = hl + rg * 8 * Hd;
#pragma unroll 4
    for (int k = 0; k < Hd; ++k) {
        float4 w = *(const float4*)(W + k * Hd + cg * 4);
#pragma unroll
        for (int i = 0; i < 8; ++i) {
            float hv = hb[i * Hd + k];
            acc[i][0] = fmaf(hv, w.x, acc[i][0]);
            acc[i][1] = fmaf(hv, w.y, acc[i][1]);
            acc[i][2] = fmaf(hv, w.z, acc[i][2]);
            acc[i][3] = fmaf(hv, w.w, acc[i][3]);
        }
    }
#pragma unroll
    for (int i = 0; i < 8; ++i) {
        int r = row0 + rg * 8 + i;
        if (r < Nn) {
            float s = dinv[r];
            float4 o = make_float4(acc[i][0] * s, acc[i][1] * s, acc[i][2] * s, acc[i][3] * s);
            *(float4*)(hw + (size_t)r * Hd + cg * 4) = o;
        }
    }
}

// ---------------- aggregation: h[i] = relu(dinv[i]*(hw[i] + sum_src hw[src]) + b) ----
// one wave per node (contiguous 512 B gather per edge = minimal line requests),
// 4-edge unroll for in-flight depth, nontemporal csr loads.
__global__ __launch_bounds__(256) void agg_kernel(const float* __restrict__ hw,
                            const int* __restrict__ row_ptr, const int* __restrict__ csr_src,
                            const float* __restrict__ dinv, const float* __restrict__ bias,
                            float* __restrict__ hout) {
    int node = blockIdx.x * 4 + (threadIdx.x >> 6);
    if (node >= Nn) return;
    int lane = threadIdx.x & 63;
    const v2f* hw2 = (const v2f*)hw;
    v2f a0 = hw2[(size_t)node * 64 + lane];   // self loop (hw pre-scaled by dinv[src])
    v2f a1 = 0.f, a2 = 0.f, a3 = 0.f;
    int e0 = row_ptr[node], e1 = row_ptr[node + 1];
    int e = e0;
    for (; e + 3 < e1; e += 4) {
        int s0 = __builtin_nontemporal_load(csr_src + e);
        int s1 = __builtin_nontemporal_load(csr_src + e + 1);
        int s2 = __builtin_nontemporal_load(csr_src + e + 2);
        int s3 = __builtin_nontemporal_load(csr_src + e + 3);
        a0 += hw2[(size_t)s0 * 64 + lane];
        a1 += hw2[(size_t)s1 * 64 + lane];
        a2 += hw2[(size_t)s2 * 64 + lane];
        a3 += hw2[(size_t)s3 * 64 + lane];
    }
    for (; e < e1; ++e) {
        int s0 = __builtin_nontemporal_load(csr_src + e);
        a0 += hw2[(size_t)s0 * 64 + lane];
    }
    v2f acc = (a0 + a1) + (a2 + a3);
    float d = dinv[node];
    v2f bv = ((const v2f*)bias)[lane];
    v2f o;
    o.x = fmaxf(fmaf(d, acc.x, bv.x), 0.f);
    o.y = fmaxf(fmaf(d, acc.y, bv.y), 0.f);
    ((v2f*)hout)[(size_t)node * 64 + lane] = o;
}

// ---------------- top-K per batch + gather pooled tile to xcg ----------------
__global__ __launch_bounds__(256) void topk_kernel(const float* __restrict__ h,
                            const int* __restrict__ bstart, float* __restrict__ xcg) {
    __shared__ float vals[CAP];
    __shared__ float rv[4];
    __shared__ int ri[4];
    __shared__ int selS[Kt];
    int b = blockIdx.x, tid = threadIdx.x;
    int s0 = bstart[b], s1 = bstart[b + 1];
    int n = s1 - s0;
    int nc = n < CAP ? n : CAP;
    for (int j = tid; j < nc; j += 256)
        vals[j] = h[(size_t)(s0 + j) * Hd + (Hd - 1)];
    __syncthreads();
    for (int k = 0; k < Kt; ++k) {
        float bv = -1.f;
        int bi = 0x7fffffff;
        for (int j = tid; j < nc; j += 256) {
            float v = vals[j];
            if (v > bv || (v == bv && j < bi)) { bv = v; bi = j; }
        }
        for (int off = 32; off > 0; off >>= 1) {
            float ov = __shfl_down(bv, off);
            int oi = __shfl_down(bi, off);
            if (ov > bv || (ov == bv && oi < bi)) { bv = ov; bi = oi; }
        }
        int wid = tid >> 6;
        if ((tid & 63) == 0) { rv[wid] = bv; ri[wid] = bi; }
        __syncthreads();
        if (tid == 0) {
            float fv = rv[0]; int fi = ri[0];
            for (int w = 1; w < 4; ++w) {
                if (rv[w] > fv || (rv[w] == fv && ri[w] < fi)) { fv = rv[w]; fi = ri[w]; }
            }
            if (k < n) {
                selS[k] = s0 + fi;
                vals[fi] = -1.f;   // relu output >= 0, so -1 can never win again
            } else {
                selS[k] = -1;
            }
        }
        __syncthreads();
    }
    // gather pooled tile: xcg[b][t][c]
    for (int i = tid; i < Kt * Hd; i += 256) {
        int t = i >> 7, c = i & 127;
        int s = selS[t];
        xcg[((size_t)b * Kt + t) * Hd + c] = (s >= 0) ? h[(size_t)s * Hd + c] : 0.f;
    }
}

// ---------------- conv: flatg[b][o][t] = relu(conv_b[o] + xc . w) -----------
__global__ __launch_bounds__(256) void conv_kernel(const float* __restrict__ xcg,
                            const float* __restrict__ wT2, const float* __restrict__ conv_b,
                            float* __restrict__ flatg) {
    __shared__ float xcl[Kt][130];
    int b = blockIdx.x, q = blockIdx.y;
    int o0 = q * CVO;
    int tid = threadIdx.x;
    for (int i = tid; i < Kt * 32; i += 256) {   // 960 float4
        int t = i >> 5, c4 = i & 31;
        float4 v = ((const float4*)(xcg + ((size_t)b * Kt + t) * Hd))[c4];
        float2* dst = (float2*)&xcl[t][c4 * 4];
        dst[0] = make_float2(v.x, v.y);
        dst[1] = make_float2(v.z, v.w);
    }
    __syncthreads();
    int idx = tid;
    if (idx < CVO * LOUT) {
        int op = idx / LOUT, t = idx - op * LOUT;
        int o = o0 + op;
        float acc = conv_b[o];
#pragma unroll
        for (int k = 0; k < KW; ++k) {
            const float* xr = &xcl[t + k][0];
            const float* wr = wT2 + ((size_t)o * KW + k) * Hd;
#pragma unroll 8
            for (int c4 = 0; c4 < 32; ++c4) {
                float2 xa = *(const float2*)(xr + c4 * 4);
                float2 xb = *(const float2*)(xr + c4 * 4 + 2);
                float4 wv = *(const float4*)(wr + c4 * 4);
                acc = fmaf(xa.x, wv.x, acc);
                acc = fmaf(xa.y, wv.y, acc);
                acc = fmaf(xb.x, wv.z, acc);
                acc = fmaf(xb.y, wv.w, acc);
            }
        }
        flatg[((size_t)b * CO + o) * LOUT + t] = fmaxf(acc, 0.f);
    }
}

// ---------------- merged lin1 + relu + lin2: one block per batch ------------
// flat[b] (832 floats) staged in LDS; thread = h + 128*half computes a half-
// range partial of z[h] with coalesced l1w loads (consecutive h lanes).
__global__ __launch_bounds__(256) void head2_kernel(const float* __restrict__ flatg,
                            const float* __restrict__ l1w, const float* __restrict__ l1b,
                            const float* __restrict__ l2w, const float* __restrict__ l2b,
                            float* __restrict__ out) {
    __shared__ float fl[CO * LOUT];     // 832
    __shared__ float pz[2][Hd];
    __shared__ float z[Hd];
    int b = blockIdx.x, tid = threadIdx.x;
    for (int i = tid; i < CO * LOUT; i += 256)
        fl[i] = flatg[(size_t)b * (CO * LOUT) + i];
    __syncthreads();
    int hh = tid & 127, half = tid >> 7;
    int m0 = half * 416;
    float acc = 0.f;
#pragma unroll 8
    for (int m = 0; m < 416; ++m)
        acc = fmaf(fl[m0 + m], l1w[(size_t)(m0 + m) * Hd + hh], acc);
    pz[half][hh] = acc;
    __syncthreads();
    if (tid < Hd)
        z[tid] = fmaxf(pz[0][tid] + pz[1][tid] + l1b[tid], 0.f);
    __syncthreads();
    if (tid < 10) {
        float a2 = l2b[tid];
        for (int j = 0; j < Hd; ++j)
            a2 = fmaf(z[j], l2w[j * 10 + tid], a2);
        out[b * 10 + tid] = a2;
    }
}

extern "C" void kernel_launch(void* const* d_in, const int* in_sizes, int n_in,
                              void* d_out, int out_size, void* d_ws, size_t ws_size,
                              hipStream_t stream) {
    const float* x      = (const float*)d_in[0];
    const int*   ei     = (const int*)d_in[1];
    const int*   batch  = (const int*)d_in[2];
    const float* W0     = (const float*)d_in[3];
    const float* b0     = (const float*)d_in[4];
    const float* W1     = (const float*)d_in[5];
    const float* b1     = (const float*)d_in[6];
    const float* W2     = (const float*)d_in[7];
    const float* b2     = (const float*)d_in[8];
    const float* conv_w = (const float*)d_in[9];
    const float* conv_b = (const float*)d_in[10];
    const float* l1w    = (const float*)d_in[11];
    const float* l1b    = (const float*)d_in[12];
    const float* l2w    = (const float*)d_in[13];
    const float* l2b    = (const float*)d_in[14];
    float* out = (float*)d_out;

    // workspace layout
    int* wsI = (int*)d_ws;
    size_t off = 0;
    int*   deg_i   = wsI + off; off += Nn;
    int*   cnt     = wsI + off; off += Nn;
    int*   row_ptr = wsI + off; off += 50004;
    int*   bstart  = wsI + off; off += 132;
    float* dinv    = (float*)(wsI + off); off += Nn;
    int*   bsum    = wsI + off; off += 256;
    int*   boff    = wsI + off; off += 256;
    int*   csr_src = wsI + off; off += Ee;
    off = (off + 3) & ~(size_t)3;        // 16B align
    float* hw    = (float*)(wsI + off); off += (size_t)Nn * Hd;
    float* hbuf  = (float*)(wsI + off); off += (size_t)Nn * Hd;
    float* xcg   = (float*)(wsI + off); off += (size_t)Bg * Kt * Hd;
    float* wT2   = (float*)(wsI + off); off += CO * KW * Hd;
    float* flatg = (float*)(wsI + off); off += (size_t)Bg * CO * LOUT;

    // 1. init (+ conv_w transpose)
    init_kernel<<<(Nn + 255) / 256, 256, 0, stream>>>(deg_i, cnt, bstart, conv_w, wT2);
    // 2. degree histogram + batch starts
    count_kernel<<<(Ee + 255) / 256, 256, 0, stream>>>(ei, batch, deg_i, bstart);
    // 3. multi-block exclusive scan -> row_ptr, dinv; fix bstart
    scanA_kernel<<<SCB, 256, 0, stream>>>(deg_i, dinv, bsum);
    scanB_kernel<<<1, 256, 0, stream>>>(bsum, boff, bstart);
    scanC_kernel<<<SCB, 256, 0, stream>>>(deg_i, boff, row_ptr);
    // 4. CSR fill
    fill_kernel<<<(Ee + 255) / 256, 256, 0, stream>>>(ei, row_ptr, cnt, csr_src);

    // 5. three GCN layers
    dim3 mmGrid((Nn + MMR - 1) / MMR);
    dim3 aggGrid((Nn + 3) / 4);
    mm_kernel<<<mmGrid, 256, 0, stream>>>(x, W0, dinv, hw);
    agg_kernel<<<aggGrid, 256, 0, stream>>>(hw, row_ptr, csr_src, dinv, b0, hbuf);
    mm_kernel<<<mmGrid, 256, 0, stream>>>(hbuf, W1, dinv, hw);
    agg_kernel<<<aggGrid, 256, 0, stream>>>(hw, row_ptr, csr_src, dinv, b1, hbuf);
    mm_kernel<<<mmGrid, 256, 0, stream>>>(hbuf, W2, dinv, hw);
    agg_kernel<<<aggGrid, 256, 0, stream>>>(hw, row_ptr, csr_src, dinv, b2, hbuf);

    // 6. sort-pool top-K + gather
    topk_kernel<<<Bg, 256, 0, stream>>>(hbuf, bstart, xcg);
    // 7. head: conv -> (lin1+lin2 merged)
    conv_kernel<<<dim3(Bg, CO / CVO), 256, 0, stream>>>(xcg, wT2, conv_b, flatg);
    head2_kernel<<<Bg, 256, 0, stream>>>(flatg, l1w, l1b, l2w, l2b, out);
}

// Round 9
// 483.930 us; speedup vs baseline: 1.4106x; 1.0370x over previous
//
#include <hip/hip_runtime.h>
#include <math.h>

#define Nn 50000
#define Ee 600000
#define Bg 128      // batches (graphs)
#define Hd 128      // hidden dim
#define Kt 30       // sortpool K
#define CO 32       // conv out channels
#define KW 5        // conv kernel
#define LOUT 26     // K - KW + 1
#define CAP 2048    // per-batch node cap for topk LDS (max real count ~460)
#define SCB 196     // ceil(50000/256) scan blocks
#define CVO 8       // conv o's per block (grid y = CO/CVO = 4)

typedef float v2f __attribute__((ext_vector_type(2)));
typedef short bf16x8 __attribute__((ext_vector_type(8)));
typedef float f32x4 __attribute__((ext_vector_type(4)));

// bf16 round-to-nearest-even helpers (branchless, finite inputs)
__device__ __forceinline__ unsigned short bfr(float v) {
    unsigned u = __builtin_bit_cast(unsigned, v);
    unsigned r = (u + 0x7FFFu + ((u >> 16) & 1u)) >> 16;
    return (unsigned short)r;
}
__device__ __forceinline__ float bff(unsigned short h) {
    unsigned u = ((unsigned)h) << 16;
    return __builtin_bit_cast(float, u);
}

// ---------------- init (+ conv_w transpose folded in) ----------------
__global__ void init_kernel(int* __restrict__ deg_i, int* __restrict__ cnt,
                            int* __restrict__ bstart,
                            const float* __restrict__ conv_w, float* __restrict__ wT2) {
    int i = blockIdx.x * 256 + threadIdx.x;
    if (i < Nn) { deg_i[i] = 1; cnt[i] = 0; }   // deg starts at 1 (self loop)
    if (i <= Bg) bstart[i] = Nn;                // sentinel
    if (i < CO * KW * Hd) {                     // wT2[o][k][ci] = conv_w[o][ci][k]
        int ci = i & 127;
        int r = i >> 7;          // o*KW + k
        int o = r / KW, k = r - o * KW;
        wT2[i] = conv_w[((size_t)o * Hd + ci) * KW + k];
    }
}

// ---------------- W 3-way split+pack into MFMA B-fragment layout ----------------
// Bp{h,m,l}[l][(kc*8+n)*64+lane][j] = bf16 splits of W_l[kc*32+(lane>>4)*8+j][n*16+(lane&15)]
__global__ void wprep_kernel(const float* __restrict__ W0, const float* __restrict__ W1,
                             const float* __restrict__ W2,
                             ushort* __restrict__ Bph, ushort* __restrict__ Bpm,
                             ushort* __restrict__ Bpl) {
    int t = blockIdx.x * 256 + threadIdx.x;   // 3*2048 total
    if (t >= 3 * 2048) return;
    int l = t >> 11;
    int r = t & 2047;
    int kc = r >> 9;
    int n = (r >> 6) & 7;
    int lane = r & 63;
    int m = lane & 15, kq = lane >> 4;
    const float* W = (l == 0) ? W0 : (l == 1) ? W1 : W2;
    int col = n * 16 + m;
    size_t off = ((size_t)l * 2048 + (size_t)((kc * 8 + n) * 64 + lane)) * 8;
#pragma unroll
    for (int j = 0; j < 8; ++j) {
        float v = W[(size_t)(kc * 32 + kq * 8 + j) * Hd + col];
        unsigned short h = bfr(v);
        float r1 = v - bff(h);
        unsigned short mid = bfr(r1);
        Bph[off + j] = h;
        Bpm[off + j] = mid;
        Bpl[off + j] = bfr(r1 - bff(mid));
    }
}

// ---------------- degree histogram + batch starts (boundary detect) ----------
__global__ void count_kernel(const int* __restrict__ ei, const int* __restrict__ batch,
                             int* __restrict__ deg_i, int* __restrict__ bstart) {
    int i = blockIdx.x * 256 + threadIdx.x;
    if (i < Ee) atomicAdd(&deg_i[ei[Ee + i]], 1);       // col = edge_index[1]
    if (i < Nn) {
        int b = batch[i];
        if (i == 0) {
            bstart[b] = 0;
        } else {
            int bp = batch[i - 1];
            if (bp != b) bstart[b] = i;
        }
    }
}

// ---------------- scan phase A: block sums of (deg-1), dinv ----------------
__global__ __launch_bounds__(256) void scanA_kernel(const int* __restrict__ deg_i,
                            float* __restrict__ dinv, int* __restrict__ bsum) {
    __shared__ int s[256];
    int tid = threadIdx.x;
    int i = blockIdx.x * 256 + tid;
    int v = 0;
    if (i < Nn) {
        int d = deg_i[i];
        dinv[i] = 1.0f / sqrtf((float)d);
        v = d - 1;
    }
    s[tid] = v;
    __syncthreads();
    for (int off = 128; off > 0; off >>= 1) {
        if (tid < off) s[tid] += s[tid + off];
        __syncthreads();
    }
    if (tid == 0) bsum[blockIdx.x] = s[0];
}

// ---------------- scan phase B: scan block sums; fix empty batches ----------
__global__ __launch_bounds__(256) void scanB_kernel(const int* __restrict__ bsum,
                            int* __restrict__ boff, int* __restrict__ bstart) {
    __shared__ int s[256];
    int tid = threadIdx.x;
    int v = (tid < SCB) ? bsum[tid] : 0;
    s[tid] = v;
    __syncthreads();
    for (int off = 1; off < 256; off <<= 1) {
        int t = (tid >= off) ? s[tid - off] : 0;
        __syncthreads();
        s[tid] += t;
        __syncthreads();
    }
    if (tid < SCB) boff[tid] = s[tid] - v;   // exclusive
    if (tid == 0) {   // empty batches inherit next start (batch array sorted)
        for (int b = Bg - 1; b >= 0; --b)
            if (bstart[b] == Nn) bstart[b] = bstart[b + 1];
    }
}

// ---------------- scan phase C: row_ptr = offset + local inclusive scan -----
__global__ __launch_bounds__(256) void scanC_kernel(const int* __restrict__ deg_i,
                            const int* __restrict__ boff, int* __restrict__ row_ptr) {
    __shared__ int s[256];
    int tid = threadIdx.x;
    int i = blockIdx.x * 256 + tid;
    int v = (i < Nn) ? deg_i[i] - 1 : 0;
    s[tid] = v;
    __syncthreads();
    for (int off = 1; off < 256; off <<= 1) {
        int t = (tid >= off) ? s[tid - off] : 0;
        __syncthreads();
        s[tid] += t;
        __syncthreads();
    }
    if (i < Nn) row_ptr[i + 1] = s[tid] + boff[blockIdx.x];
    if (i == 0) row_ptr[0] = 0;
}

// ---------------- CSR fill (edges grouped by destination col) ----------------
__global__ void fill_kernel(const int* __restrict__ ei, const int* __restrict__ row_ptr,
                            int* __restrict__ cnt, int* __restrict__ csr_src) {
    int e = blockIdx.x * 256 + threadIdx.x;
    if (e >= Ee) return;
    int c = ei[Ee + e];
    int r = ei[e];
    int p = row_ptr[c] + atomicAdd(&cnt[c], 1);
    csr_src[p] = r;
}

// ---------------- MFMA matmul: hw[i] = dinv[i] * (Hin[i] @ W) ----------------
// 3-way split-bf16 (near-fp32): a = a0+a1+a2 (24 mantissa bits), W pre-packed
// in 3 levels. Retained products: a0b0,a1b0,a0b1,a1b1,a2b0,a0b2 (dropped terms
// ~2^-27 relative). Block: 64 rows x 128 cols, 4 waves, no LDS.
// mfma_f32_16x16x32_bf16: A[m=lane&15][k=quad*8+j]; B[k=quad*8+j][n=lane&15];
// D col=lane&15, row=quad*4+reg  (m89/m91-verified mappings).
__global__ __launch_bounds__(256) void mmx_kernel(const float* __restrict__ Hin,
                            const ushort* __restrict__ Bph, const ushort* __restrict__ Bpm,
                            const ushort* __restrict__ Bpl,
                            const float* __restrict__ dinv, float* __restrict__ hw) {
    int tid = threadIdx.x;
    int w = tid >> 6, lane = tid & 63;
    int m = lane & 15, kq = lane >> 4;
    int rowA = blockIdx.x * 64 + w * 16 + m;
    bool va = rowA < Nn;
    const float* ap = Hin + (size_t)rowA * Hd;
    f32x4 acc[8];
#pragma unroll
    for (int n = 0; n < 8; ++n) acc[n] = (f32x4)0.f;
#pragma unroll
    for (int kc = 0; kc < 4; ++kc) {
        bf16x8 a0 = (bf16x8)0, a1 = (bf16x8)0, a2 = (bf16x8)0;
        if (va) {
            float av[8];
            *(float4*)&av[0] = *(const float4*)(ap + kc * 32 + kq * 8);
            *(float4*)&av[4] = *(const float4*)(ap + kc * 32 + kq * 8 + 4);
#pragma unroll
            for (int j = 0; j < 8; ++j) {
                unsigned short h = bfr(av[j]);
                float r1 = av[j] - bff(h);
                unsigned short mid = bfr(r1);
                a0[j] = (short)h;
                a1[j] = (short)mid;
                a2[j] = (short)bfr(r1 - bff(mid));
            }
        }
        const ushort* bhp = Bph + (size_t)((kc * 8) * 64 + lane) * 8;
        const ushort* bmp = Bpm + (size_t)((kc * 8) * 64 + lane) * 8;
        const ushort* blp = Bpl + (size_t)((kc * 8) * 64 + lane) * 8;
#pragma unroll
        for (int n = 0; n < 8; ++n) {
            bf16x8 b0 = *(const bf16x8*)(bhp + (size_t)n * 64 * 8);
            bf16x8 b1 = *(const bf16x8*)(bmp + (size_t)n * 64 * 8);
            bf16x8 b2 = *(const bf16x8*)(blp + (size_t)n * 64 * 8);
            acc[n] = __builtin_amdgcn_mfma_f32_16x16x32_bf16(a0, b0, acc[n], 0, 0, 0);
            acc[n] = __builtin_amdgcn_mfma_f32_16x16x32_bf16(a1, b0, acc[n], 0, 0, 0);
            acc[n] = __builtin_amdgcn_mfma_f32_16x16x32_bf16(a0, b1, acc[n], 0, 0, 0);
            acc[n] = __builtin_amdgcn_mfma_f32_16x16x32_bf16(a1, b1, acc[n], 0, 0, 0);
            acc[n] = __builtin_amdgcn_mfma_f32_16x16x32_bf16(a2, b0, acc[n], 0, 0, 0);
            acc[n] = __builtin_amdgcn_mfma_f32_16x16x32_bf16(a0, b2, acc[n], 0, 0, 0);
        }
    }
    int rbase = blockIdx.x * 64 + w * 16 + kq * 4;
#pragma unroll
    for (int reg = 0; reg < 4; ++reg) {
        int r = rbase + reg;
        if (r < Nn) {
            float s = dinv[r];
#pragma unroll
            for (int n = 0; n < 8; ++n)
                hw[(size_t)r * Hd + n * 16 + m] = acc[n][reg] * s;
        }
    }
}

// ---------------- aggregation: h[i] = relu(dinv[i]*(hw[i] + sum_src hw[src]) + b) ----
// one wave per node (contiguous 512 B gather per edge = minimal line requests),
// 4-edge unroll for in-flight depth, nontemporal csr loads.
__global__ __launch_bounds__(256) void agg_kernel(const float* __restrict__ hw,
                            const int* __restrict__ row_ptr, const int* __restrict__ csr_src,
                            const float* __restrict__ dinv, const float* __restrict__ bias,
                            float* __restrict__ hout) {
    int node = blockIdx.x * 4 + (threadIdx.x >> 6);
    if (node >= Nn) return;
    int lane = threadIdx.x & 63;
    const v2f* hw2 = (const v2f*)hw;
    v2f a0 = hw2[(size_t)node * 64 + lane];   // self loop (hw pre-scaled by dinv[src])
    v2f a1 = 0.f, a2 = 0.f, a3 = 0.f;
    int e0 = row_ptr[node], e1 = row_ptr[node + 1];
    int e = e0;
    for (; e + 3 < e1; e += 4) {
        int s0 = __builtin_nontemporal_load(csr_src + e);
        int s1 = __builtin_nontemporal_load(csr_src + e + 1);
        int s2 = __builtin_nontemporal_load(csr_src + e + 2);
        int s3 = __builtin_nontemporal_load(csr_src + e + 3);
        a0 += hw2[(size_t)s0 * 64 + lane];
        a1 += hw2[(size_t)s1 * 64 + lane];
        a2 += hw2[(size_t)s2 * 64 + lane];
        a3 += hw2[(size_t)s3 * 64 + lane];
    }
    for (; e < e1; ++e) {
        int s0 = __builtin_nontemporal_load(csr_src + e);
        a0 += hw2[(size_t)s0 * 64 + lane];
    }
    v2f acc = (a0 + a1) + (a2 + a3);
    float d = dinv[node];
    v2f bv = ((const v2f*)bias)[lane];
    v2f o;
    o.x = fmaxf(fmaf(d, acc.x, bv.x), 0.f);
    o.y = fmaxf(fmaf(d, acc.y, bv.y), 0.f);
    ((v2f*)hout)[(size_t)node * 64 + lane] = o;
}

// ---------------- top-K per batch + gather pooled tile to xcg ----------------
__global__ __launch_bounds__(256) void topk_kernel(const float* __restrict__ h,
                            const int* __restrict__ bstart, float* __restrict__ xcg) {
    __shared__ float vals[CAP];
    __shared__ float rv[4];
    __shared__ int ri[4];
    __shared__ int selS[Kt];
    int b = blockIdx.x, tid = threadIdx.x;
    int s0 = bstart[b], s1 = bstart[b + 1];
    int n = s1 - s0;
    int nc = n < CAP ? n : CAP;
    for (int j = tid; j < nc; j += 256)
        vals[j] = h[(size_t)(s0 + j) * Hd + (Hd - 1)];
    __syncthreads();
    for (int k = 0; k < Kt; ++k) {
        float bv = -1.f;
        int bi = 0x7fffffff;
        for (int j = tid; j < nc; j += 256) {
            float v = vals[j];
            if (v > bv || (v == bv && j < bi)) { bv = v; bi = j; }
        }
        for (int off = 32; off > 0; off >>= 1) {
            float ov = __shfl_down(bv, off);
            int oi = __shfl_down(bi, off);
            if (ov > bv || (ov == bv && oi < bi)) { bv = ov; bi = oi; }
        }
        int wid = tid >> 6;
        if ((tid & 63) == 0) { rv[wid] = bv; ri[wid] = bi; }
        __syncthreads();
        if (tid == 0) {
            float fv = rv[0]; int fi = ri[0];
            for (int w = 1; w < 4; ++w) {
                if (rv[w] > fv || (rv[w] == fv && ri[w] < fi)) { fv = rv[w]; fi = ri[w]; }
            }
            if (k < n) {
                selS[k] = s0 + fi;
                vals[fi] = -1.f;   // relu output >= 0, so -1 can never win again
            } else {
                selS[k] = -1;
            }
        }
        __syncthreads();
    }
    // gather pooled tile: xcg[b][t][c]
    for (int i = tid; i < Kt * Hd; i += 256) {
        int t = i >> 7, c = i & 127;
        int s = selS[t];
        xcg[((size_t)b * Kt + t) * Hd + c] = (s >= 0) ? h[(size_t)s * Hd + c] : 0.f;
    }
}

// ---------------- conv: flatg[b][o][t] = relu(conv_b[o] + xc . w) -----------
__global__ __launch_bounds__(256) void conv_kernel(const float* __restrict__ xcg,
                            const float* __restrict__ wT2, const float* __restrict__ conv_b,
                            float* __restrict__ flatg) {
    __shared__ float xcl[Kt][130];
    int b = blockIdx.x, q = blockIdx.y;
    int o0 = q * CVO;
    int tid = threadIdx.x;
    for (int i = tid; i < Kt * 32; i += 256) {   // 960 float4
        int t = i >> 5, c4 = i & 31;
        float4 v = ((const float4*)(xcg + ((size_t)b * Kt + t) * Hd))[c4];
        float2* dst = (float2*)&xcl[t][c4 * 4];
        dst[0] = make_float2(v.x, v.y);
        dst[1] = make_float2(v.z, v.w);
    }
    __syncthreads();
    int idx = tid;
    if (idx < CVO * LOUT) {
        int op = idx / LOUT, t = idx - op * LOUT;
        int o = o0 + op;
        float acc = conv_b[o];
#pragma unroll
        for (int k = 0; k < KW; ++k) {
            const float* xr = &xcl[t + k][0];
            const float* wr = wT2 + ((size_t)o * KW + k) * Hd;
#pragma unroll 8
            for (int c4 = 0; c4 < 32; ++c4) {
                float2 xa = *(const float2*)(xr + c4 * 4);
                float2 xb = *(const float2*)(xr + c4 * 4 + 2);
                float4 wv = *(const float4*)(wr + c4 * 4);
                acc = fmaf(xa.x, wv.x, acc);
                acc = fmaf(xa.y, wv.y, acc);
                acc = fmaf(xb.x, wv.z, acc);
                acc = fmaf(xb.y, wv.w, acc);
            }
        }
        flatg[((size_t)b * CO + o) * LOUT + t] = fmaxf(acc, 0.f);
    }
}

// ---------------- merged lin1 + relu + lin2: one block per batch ------------
__global__ __launch_bounds__(256) void head2_kernel(const float* __restrict__ flatg,
                            const float* __restrict__ l1w, const float* __restrict__ l1b,
                            const float* __restrict__ l2w, const float* __restrict__ l2b,
                            float* __restrict__ out) {
    __shared__ float fl[CO * LOUT];     // 832
    __shared__ float pz[2][Hd];
    __shared__ float z[Hd];
    int b = blockIdx.x, tid = threadIdx.x;
    for (int i = tid; i < CO * LOUT; i += 256)
        fl[i] = flatg[(size_t)b * (CO * LOUT) + i];
    __syncthreads();
    int hh = tid & 127, half = tid >> 7;
    int m0 = half * 416;
    float acc = 0.f;
#pragma unroll 8
    for (int m = 0; m < 416; ++m)
        acc = fmaf(fl[m0 + m], l1w[(size_t)(m0 + m) * Hd + hh], acc);
    pz[half][hh] = acc;
    __syncthreads();
    if (tid < Hd)
        z[tid] = fmaxf(pz[0][tid] + pz[1][tid] + l1b[tid], 0.f);
    __syncthreads();
    if (tid < 10) {
        float a2 = l2b[tid];
        for (int j = 0; j < Hd; ++j)
            a2 = fmaf(z[j], l2w[j * 10 + tid], a2);
        out[b * 10 + tid] = a2;
    }
}

extern "C" void kernel_launch(void* const* d_in, const int* in_sizes, int n_in,
                              void* d_out, int out_size, void* d_ws, size_t ws_size,
                              hipStream_t stream) {
    const float* x      = (const float*)d_in[0];
    const int*   ei     = (const int*)d_in[1];
    const int*   batch  = (const int*)d_in[2];
    const float* W0     = (const float*)d_in[3];
    const float* b0     = (const float*)d_in[4];
    const float* W1     = (const float*)d_in[5];
    const float* b1     = (const float*)d_in[6];
    const float* W2     = (const float*)d_in[7];
    const float* b2     = (const float*)d_in[8];
    const float* conv_w = (const float*)d_in[9];
    const float* conv_b = (const float*)d_in[10];
    const float* l1w    = (const float*)d_in[11];
    const float* l1b    = (const float*)d_in[12];
    const float* l2w    = (const float*)d_in[13];
    const float* l2b    = (const float*)d_in[14];
    float* out = (float*)d_out;

    // workspace layout
    int* wsI = (int*)d_ws;
    size_t off = 0;
    int*   deg_i   = wsI + off; off += Nn;
    int*   cnt     = wsI + off; off += Nn;
    int*   row_ptr = wsI + off; off += 50004;
    int*   bstart  = wsI + off; off += 132;
    float* dinv    = (float*)(wsI + off); off += Nn;
    int*   bsum    = wsI + off; off += 256;
    int*   boff    = wsI + off; off += 256;
    int*   csr_src = wsI + off; off += Ee;
    off = (off + 3) & ~(size_t)3;        // 16B align
    ushort* Bph  = (ushort*)(wsI + off); off += 3 * 16384 / 2;   // packed W split hi
    ushort* Bpm  = (ushort*)(wsI + off); off += 3 * 16384 / 2;   // packed W split mid
    ushort* Bpl  = (ushort*)(wsI + off); off += 3 * 16384 / 2;   // packed W split lo
    float* hw    = (float*)(wsI + off); off += (size_t)Nn * Hd;
    float* hbuf  = (float*)(wsI + off); off += (size_t)Nn * Hd;
    float* xcg   = (float*)(wsI + off); off += (size_t)Bg * Kt * Hd;
    float* wT2   = (float*)(wsI + off); off += CO * KW * Hd;
    float* flatg = (float*)(wsI + off); off += (size_t)Bg * CO * LOUT;

    // 1. init (+ conv_w transpose), W split+pack
    init_kernel<<<(Nn + 255) / 256, 256, 0, stream>>>(deg_i, cnt, bstart, conv_w, wT2);
    wprep_kernel<<<24, 256, 0, stream>>>(W0, W1, W2, Bph, Bpm, Bpl);
    // 2. degree histogram + batch starts
    count_kernel<<<(Ee + 255) / 256, 256, 0, stream>>>(ei, batch, deg_i, bstart);
    // 3. multi-block exclusive scan -> row_ptr, dinv; fix bstart
    scanA_kernel<<<SCB, 256, 0, stream>>>(deg_i, dinv, bsum);
    scanB_kernel<<<1, 256, 0, stream>>>(bsum, boff, bstart);
    scanC_kernel<<<SCB, 256, 0, stream>>>(deg_i, boff, row_ptr);
    // 4. CSR fill
    fill_kernel<<<(Ee + 255) / 256, 256, 0, stream>>>(ei, row_ptr, cnt, csr_src);

    // 5. three GCN layers (MFMA matmul + gather-aggregate)
    dim3 mmGrid((Nn + 63) / 64);
    dim3 aggGrid((Nn + 3) / 4);
    mmx_kernel<<<mmGrid, 256, 0, stream>>>(x, Bph, Bpm, Bpl, dinv, hw);
    agg_kernel<<<aggGrid, 256, 0, stream>>>(hw, row_ptr, csr_src, dinv, b0, hbuf);
    mmx_kernel<<<mmGrid, 256, 0, stream>>>(hbuf, Bph + 16384, Bpm + 16384, Bpl + 16384, dinv, hw);
    agg_kernel<<<aggGrid, 256, 0, stream>>>(hw, row_ptr, csr_src, dinv, b1, hbuf);
    mmx_kernel<<<mmGrid, 256, 0, stream>>>(hbuf, Bph + 32768, Bpm + 32768, Bpl + 32768, dinv, hw);
    agg_kernel<<<aggGrid, 256, 0, stream>>>(hw, row_ptr, csr_src, dinv, b2, hbuf);

    // 6. sort-pool top-K + gather
    topk_kernel<<<Bg, 256, 0, stream>>>(hbuf, bstart, xcg);
    // 7. head: conv -> (lin1+lin2 merged)
    conv_kernel<<<dim3(Bg, CO / CVO), 256, 0, stream>>>(xcg, wT2, conv_b, flatg);
    head2_kernel<<<Bg, 256, 0, stream>>>(flatg, l1w, l1b, l2w, l2b, out);
}